// Round 8
// baseline (246.557 us; speedup 1.0000x reference)
//
#include <hip/hip_runtime.h>
#include <hip/hip_bf16.h>
#include <stdint.h>

#define TB 2
#define TS 2048
#define TD 1024
#define TH 16
#define THS 64
#define TK 1024  // inner dim of both GEMMs

typedef __attribute__((ext_vector_type(8))) short short8;
typedef __attribute__((ext_vector_type(4))) short short4v;
typedef __attribute__((ext_vector_type(4))) float f32x4;
typedef __attribute__((ext_vector_type(16))) float f32x16;
typedef __attribute__((ext_vector_type(4))) unsigned int uint4v;

static __device__ __forceinline__ unsigned short f2bf(float f) {
  union { float f; unsigned u; } v; v.f = f;
  unsigned r = v.u + 0x7FFFu + ((v.u >> 16) & 1u);  // RTNE
  return (unsigned short)(r >> 16);
}

static __device__ __forceinline__ float bf2f(unsigned short u) {
  union { unsigned u; float f; } v; v.u = ((unsigned)u) << 16;
  return v.f;
}

// pack two f32 -> (hi:bf16(b), lo:bf16(a))
static __device__ __forceinline__ unsigned cvtpk(float a, float b) {
  unsigned r;
  asm("v_cvt_pk_bf16_f32 %0, %1, %2" : "=v"(r) : "v"(a), "v"(b));
  return r;
}

// exchange: a.lanes[32:63] <-> b.lanes[0:31]
static __device__ __forceinline__ void swap32(unsigned& a, unsigned& b) {
  asm("v_permlane32_swap_b32 %0, %1" : "+v"(a), "+v"(b));
}

static __device__ __forceinline__ void async_copy16(const void* g, void* l) {
  __builtin_amdgcn_global_load_lds(
      (const __attribute__((address_space(1))) unsigned int*)g,
      (__attribute__((address_space(3))) unsigned int*)l, 16, 0, 0);
}

// ---------------- elementwise fp32 -> bf16 cast ----------------
__global__ __launch_bounds__(256) void k_cvt_bf16x4(const float* __restrict__ in,
                                                    ushort4* __restrict__ out, int n4) {
  int i = blockIdx.x * blockDim.x + threadIdx.x;
  if (i >= n4) return;
  float4 v = ((const float4*)in)[i];
  out[i] = make_ushort4(f2bf(v.x), f2bf(v.y), f2bf(v.z), f2bf(v.w));
}

// ---------------- fp32 [R][C] -> bf16 [C][R] transpose ----------------
__global__ __launch_bounds__(256) void k_transpose_bf(const float* __restrict__ in,
                                                      unsigned short* __restrict__ out,
                                                      int R, int C) {
  __shared__ float tile[32][33];
  const int tx = threadIdx.x & 31, ty = threadIdx.x >> 5;  // ty 0..7
  const int r0 = blockIdx.y * 32, c0 = blockIdx.x * 32;
#pragma unroll
  for (int i = 0; i < 32; i += 8)
    tile[ty + i][tx] = in[(size_t)(r0 + ty + i) * C + c0 + tx];
  __syncthreads();
#pragma unroll
  for (int i = 0; i < 32; i += 8)
    out[(size_t)(c0 + ty + i) * R + r0 + tx] = f2bf(tile[tx][ty + i]);
}

// ---------------- shared GEMM core: C[128x128] tile, K=1024, A[M][K] bf16, BT[N][K] bf16 ----------------
__device__ __forceinline__ void gemm_core_k1024(const unsigned short* __restrict__ A,
                                                const unsigned short* __restrict__ BT,
                                                int m0, int n0,
                                                unsigned short* sA, unsigned short* sB,
                                                f32x4 acc[4][4]) {
  const int tid = threadIdx.x;
  const int wave = tid >> 6, lane = tid & 63;
  const int wm = wave >> 1, wn = wave & 1;

  const unsigned short* gsrc = (wave < 2) ? A : BT;
  const int row0 = (wave < 2) ? m0 : n0;
  unsigned short* lbase = (wave < 2) ? sA : sB;
  const int cw = (wave & 1) * 4;
  const size_t gr = (size_t)(row0 + cw * 16 + (lane >> 2)) * TK + (lane & 3) * 8;

#pragma unroll
  for (int mi = 0; mi < 4; ++mi)
#pragma unroll
    for (int ni = 0; ni < 4; ++ni)
      acc[mi][ni] = (f32x4){0.f, 0.f, 0.f, 0.f};

  auto stage = [&](int buf, int kt) {
    const unsigned short* g = gsrc + gr + kt * 32;
    unsigned short* l = lbase + buf * 4096 + cw * 512;
#pragma unroll
    for (int c = 0; c < 4; ++c)
      async_copy16(g + (size_t)c * 16 * TK, l + c * 512);
  };

  stage(0, 0);
  __syncthreads();

  const int l15 = lane & 15, lk8 = (lane >> 4) * 8;
  const int aoff = (wm * 64 + l15) * 32 + lk8;
  const int boff = (wn * 64 + l15) * 32 + lk8;

  for (int kt = 0; kt < TK / 32; ++kt) {
    const int buf = kt & 1;
    if (kt + 1 < TK / 32) stage(buf ^ 1, kt + 1);
    short8 af[4], bfr[4];
#pragma unroll
    for (int i = 0; i < 4; ++i) {
      af[i] = *(const short8*)&sA[buf * 4096 + aoff + i * 16 * 32];
      bfr[i] = *(const short8*)&sB[buf * 4096 + boff + i * 16 * 32];
    }
#pragma unroll
    for (int mi = 0; mi < 4; ++mi)
#pragma unroll
      for (int ni = 0; ni < 4; ++ni)
        acc[mi][ni] = __builtin_amdgcn_mfma_f32_16x16x32_bf16(af[mi], bfr[ni], acc[mi][ni], 0, 0, 0);
    __syncthreads();
  }
}

// ---------------- GEMM1: qkv = xb @ waT^T + bias -> Q/K [B,H,S,HS] and VT [B,H,HS,S] ----------------
__global__ __launch_bounds__(256) void k_gemm_qkv(const unsigned short* __restrict__ A,
                                                  const unsigned short* __restrict__ BT,
                                                  const float* __restrict__ bias,
                                                  unsigned short* __restrict__ Qo,
                                                  unsigned short* __restrict__ Ko,
                                                  unsigned short* __restrict__ VTo) {
  __shared__ unsigned short smem[4 * 64 * 68];  // 34816 B; front 32 KB doubles as sA/sB
  unsigned short* sA = smem;
  unsigned short* sB = smem + 8192;
  f32x4 acc[4][4];
  const int m0 = blockIdx.y * 128, n0 = blockIdx.x * 128;
  gemm_core_k1024(A, BT, m0, n0, sA, sB, acc);

  const int lane = threadIdx.x & 63, wave = threadIdx.x >> 6;
  const int wm = wave >> 1, wn = wave & 1;
  const int lr4 = (lane >> 4) * 4, l15 = lane & 15;

  const int col0 = n0 + wn * 64;   // 64-aligned -> one head, one region (uniform per wave)
  const int reg = col0 >> 10;      // 0:q 1:k 2:v
  const int h0 = (col0 & 1023) >> 6;
  const bool isV = (reg == 2);
  const int t0 = m0 + wm * 64;     // first row of this wave's subtile
  const int b = t0 >> 11;
  const int s0 = t0 & 2047;

  unsigned short* tw = smem + wave * (64 * 68);
#pragma unroll
  for (int mi = 0; mi < 4; ++mi) {
#pragma unroll
    for (int ni = 0; ni < 4; ++ni) {
      const int c = ni * 16 + l15;
      const float bi = bias[col0 + c];
#pragma unroll
      for (int j = 0; j < 4; ++j) {
        const int r = mi * 16 + lr4 + j;
        tw[isV ? (c * 68 + r) : (r * 68 + c)] = f2bf(acc[mi][ni][j] + bi);
      }
    }
  }
  unsigned short* outp;
  size_t rstride;
  if (isV) {        // row = d, cols = s
    outp = VTo + (((size_t)b * TH + h0) * THS) * TS + s0;
    rstride = TS;
  } else {          // row = s, cols = d
    outp = (reg == 0 ? Qo : Ko) + (((size_t)b * TH + h0) * TS + s0) * THS;
    rstride = THS;
  }
#pragma unroll
  for (int p2 = 0; p2 < 8; ++p2) {
    const int rp = p2 * 8 + (lane >> 3);
    const int co = (lane & 7) * 8;
    union { short4v h[2]; short8 s8; } u;
    u.h[0] = *(const short4v*)&tw[rp * 68 + co];
    u.h[1] = *(const short4v*)&tw[rp * 68 + co + 4];
    *(short8*)(outp + (size_t)rp * rstride + co) = u.s8;
  }
}

// ---------------- flash attention, causal, KV-SPLIT (flash-decoding style) ----------------
// Chunk table per (b,h): c in [0,96). c<64: w=c, kv [0, min(w+1,32)); c>=64: w=c-32,
// kv [32, w+1). Waves with w<32 are sole owners -> write output directly (R2 path).
// Waves with w>=32 write unnormalized O (bf16) + (m,l) (f32) partials; k_attn_combine
// merges the two halves. 3072 waves (vs 2048), max chain 32 tiles (vs 64).
// Inner loop = R2-verified math + defer-rescale + tree reductions (proven in R3/R4).
__global__ __launch_bounds__(256) void k_attn(const unsigned short* __restrict__ Q,
                                              const unsigned short* __restrict__ K,
                                              const unsigned short* __restrict__ VT,
                                              unsigned short* __restrict__ attn,
                                              unsigned short* __restrict__ pO,
                                              float2* __restrict__ pML) {
  __shared__ unsigned short sO[4][32 * 68];  // per-wave O transpose buffer, stride 68
  const int lane = threadIdx.x & 63, wave = threadIdx.x >> 6;
  const int l31 = lane & 31, h = lane >> 5;
  int c = blockIdx.x * 4 + wave;             // 0..95
  const int hh = blockIdx.y, b = blockIdx.z;
  if (b) c = 95 - c;  // complement pairing mixes long/short chunks across CUs

  int w, lo, hi, jhalf;
  if (c < 64) { w = c; lo = 0; hi = (w < 32) ? (w + 1) : 32; jhalf = 0; }
  else        { w = c - 32; lo = 32; hi = w + 1; jhalf = 1; }
  const bool partial = (w >= 32);
  const bool diag = (hi - 1 == w);           // last tile is the causal diagonal
  const int qrb = w * 32;

  const unsigned short* Qh = Q + (((size_t)b * TH + hh) * TS) * THS;
  const unsigned short* Kh = K + (((size_t)b * TH + hh) * TS) * THS;
  const unsigned short* Vh = VT + (((size_t)b * TH + hh) * THS) * TS;

  // Q B-frags: lane holds row (qrb + l31), d-chunk c2*16 + h*8
  short8 qf[4];
#pragma unroll
  for (int c2 = 0; c2 < 4; ++c2)
    qf[c2] = *(const short8*)&Qh[(size_t)(qrb + l31) * THS + c2 * 16 + h * 8];

  f32x16 o0 = {}, o1 = {};
  float m_run = -1e30f, l_run = 0.f;
  const float cl2e = 0.125f * 1.44269504088896340736f;  // scale * log2(e)
  const float THR = 8.0f / cl2e;                        // defer-rescale threshold (raw score)

  // K A-frags for first tile of the chunk
  short8 kf[4];
#pragma unroll
  for (int c2 = 0; c2 < 4; ++c2)
    kf[c2] = *(const short8*)&Kh[(size_t)(lo * 32 + l31) * THS + c2 * 16 + h * 8];

  for (int kt = lo; kt < hi; ++kt) {
    const int kb = kt * 32;
    // V^T A-frags for current tile (consumed after softmax -> latency-tolerant)
    short8 vf[2][2];
#pragma unroll
    for (int t = 0; t < 2; ++t)
#pragma unroll
      for (int c2 = 0; c2 < 2; ++c2)
        vf[t][c2] = *(const short8*)&Vh[(size_t)(t * 32 + l31) * TS + kb + c2 * 16 + h * 8];

    // S^T[k][q] accumulate over d
    f32x16 s = {};
#pragma unroll
    for (int c2 = 0; c2 < 4; ++c2)
      s = __builtin_amdgcn_mfma_f32_32x32x16_bf16(kf[c2], qf[c2], s, 0, 0, 0);

    // prefetch next K tile (in-place WAR; loads issue after mfma reads)
    if (kt + 1 < hi) {
#pragma unroll
      for (int c2 = 0; c2 < 4; ++c2)
        kf[c2] = *(const short8*)&Kh[(size_t)(kb + 32 + l31) * THS + c2 * 16 + h * 8];
    }

    // causal mask on the diagonal tile
    if (diag && kt == hi - 1) {
#pragma unroll
      for (int r = 0; r < 16; ++r)
        if ((r & 3) + 8 * (r >> 2) + 4 * h > l31) s[r] = -1e30f;
    }

    // online softmax (per-lane q = l31, replicated across halves); tree reductions
    const float ma = fmaxf(fmaxf(s[0], s[1]), fmaxf(s[2], s[3]));
    const float mb = fmaxf(fmaxf(s[4], s[5]), fmaxf(s[6], s[7]));
    const float mc = fmaxf(fmaxf(s[8], s[9]), fmaxf(s[10], s[11]));
    const float md = fmaxf(fmaxf(s[12], s[13]), fmaxf(s[14], s[15]));
    float tm = fmaxf(fmaxf(ma, mb), fmaxf(mc, md));
    tm = fmaxf(tm, __shfl_xor(tm, 32));

    float al;
    if (__all(tm <= m_run + THR)) {
      al = 1.0f;  // defer: keep old max, P bounded by exp2(8)
    } else {
      const float mn = fmaxf(m_run, tm);
      al = __builtin_amdgcn_exp2f((m_run - mn) * cl2e);
      m_run = mn;
      o0 *= al;
      o1 *= al;
    }
#pragma unroll
    for (int r = 0; r < 16; ++r)
      s[r] = __builtin_amdgcn_exp2f((s[r] - m_run) * cl2e);
    const float sa = (s[0] + s[1]) + (s[2] + s[3]);
    const float sb2 = (s[4] + s[5]) + (s[6] + s[7]);
    const float sc = (s[8] + s[9]) + (s[10] + s[11]);
    const float sd = (s[12] + s[13]) + (s[14] + s[15]);
    float ts = (sa + sb2) + (sc + sd);
    ts += __shfl_xor(ts, 32);
    l_run = l_run * al + ts;

    // P^T B-frags: pack pairs to bf16, pairwise permlane32_swap -> frag words in order
    unsigned B0 = cvtpk(s[0], s[1]), B1 = cvtpk(s[2], s[3]);
    unsigned B2 = cvtpk(s[4], s[5]), B3 = cvtpk(s[6], s[7]);
    swap32(B0, B2);
    swap32(B1, B3);
    unsigned B4 = cvtpk(s[8], s[9]), B5 = cvtpk(s[10], s[11]);
    unsigned B6 = cvtpk(s[12], s[13]), B7 = cvtpk(s[14], s[15]);
    swap32(B4, B6);
    swap32(B5, B7);
    union U { uint4v u; short8 s8; } u0, u1;
    u0.u = (uint4v){B0, B1, B2, B3};
    u1.u = (uint4v){B4, B5, B6, B7};

    o0 = __builtin_amdgcn_mfma_f32_32x32x16_bf16(vf[0][0], u0.s8, o0, 0, 0, 0);
    o0 = __builtin_amdgcn_mfma_f32_32x32x16_bf16(vf[0][1], u1.s8, o0, 0, 0, 0);
    o1 = __builtin_amdgcn_mfma_f32_32x32x16_bf16(vf[1][0], u0.s8, o1, 0, 0, 0);
    o1 = __builtin_amdgcn_mfma_f32_32x32x16_bf16(vf[1][1], u1.s8, o1, 0, 0, 0);
  }

  // epilogue: O^T -> LDS (wave-private, no barrier) -> coalesced 16B stores
  const float inv = partial ? 1.0f : (1.0f / l_run);
  unsigned* so32 = (unsigned*)&sO[wave][0];
#pragma unroll
  for (int j2 = 0; j2 < 8; ++j2) {
    const int d0 = ((2 * j2) & 3) + 8 * (j2 >> 1) + 4 * h;  // even d of the pair
    so32[l31 * 34 + (d0 >> 1)] = cvtpk(o0[2 * j2] * inv, o0[2 * j2 + 1] * inv);
    so32[l31 * 34 + ((32 + d0) >> 1)] = cvtpk(o1[2 * j2] * inv, o1[2 * j2 + 1] * inv);
  }
  if (!partial) {
#pragma unroll
    for (int p2 = 0; p2 < 4; ++p2) {
      const int rp = p2 * 8 + (lane >> 3);
      const int co = (lane & 7) * 8;
      short4v va = *(const short4v*)&sO[wave][rp * 68 + co];
      short4v vb = *(const short4v*)&sO[wave][rp * 68 + co + 4];
      unsigned short* gp = &attn[(size_t)(b * TS + qrb + rp) * TD + hh * THS + co];
      *(short4v*)gp = va;
      *(short4v*)(gp + 4) = vb;
    }
  } else {
    const int p = ((b * TH + hh) * 32 + (w - 32)) * 2 + jhalf;
    unsigned short* gp0 = pO + (size_t)p * 32 * 64;
#pragma unroll
    for (int p2 = 0; p2 < 4; ++p2) {
      const int rp = p2 * 8 + (lane >> 3);
      const int co = (lane & 7) * 8;
      union { short4v h[2]; short8 s8; } u;
      u.h[0] = *(const short4v*)&sO[wave][rp * 68 + co];
      u.h[1] = *(const short4v*)&sO[wave][rp * 68 + co + 4];
      *(short8*)(gp0 + rp * 64 + co) = u.s8;
    }
    if (h == 0) pML[p * 32 + l31] = make_float2(m_run, l_run);
  }
}

// ---------------- combine the two KV-split halves for q-tiles w>=32 ----------------
__global__ __launch_bounds__(64) void k_attn_combine(const unsigned short* __restrict__ pO,
                                                     const float2* __restrict__ pML,
                                                     unsigned short* __restrict__ attn) {
  const int d = threadIdx.x;                 // 0..63
  const int wx = blockIdx.x;                 // w-32, 0..31
  const int hh = blockIdx.y, b = blockIdx.z;
  const int p = ((b * TH + hh) * 32 + wx) * 2;
  const float cl2e = 0.125f * 1.44269504088896340736f;
  const unsigned short* oa = pO + (size_t)p * 32 * 64;
  const unsigned short* ob = oa + 32 * 64;
#pragma unroll 4
  for (int r = 0; r < 32; ++r) {
    const float2 A = pML[p * 32 + r];
    const float2 Bv = pML[(p + 1) * 32 + r];
    const float m = fmaxf(A.x, Bv.x);
    const float eA = __builtin_amdgcn_exp2f((A.x - m) * cl2e);
    const float eB = __builtin_amdgcn_exp2f((Bv.x - m) * cl2e);
    const float linv = 1.0f / (A.y * eA + Bv.y * eB);
    const float o = (bf2f(oa[r * 64 + d]) * eA + bf2f(ob[r * 64 + d]) * eB) * linv;
    attn[(size_t)(b * TS + (32 + wx) * 32 + r) * TD + hh * THS + d] = f2bf(o);
  }
}

// ---------------- GEMM2: out = attn @ wpT^T + bias (fp32 out) ----------------
__global__ __launch_bounds__(256) void k_gemm_proj(const unsigned short* __restrict__ A,
                                                   const unsigned short* __restrict__ BT,
                                                   const float* __restrict__ bias,
                                                   float* __restrict__ out) {
  __shared__ unsigned short sA[2 * 4096];
  __shared__ unsigned short sB[2 * 4096];
  f32x4 acc[4][4];
  const int m0 = blockIdx.y * 128, n0 = blockIdx.x * 128;
  gemm_core_k1024(A, BT, m0, n0, sA, sB, acc);

  const int lane = threadIdx.x & 63, wave = threadIdx.x >> 6;
  const int wm = wave >> 1, wn = wave & 1;
  const int lr4 = (lane >> 4) * 4, l15 = lane & 15;
#pragma unroll
  for (int mi = 0; mi < 4; ++mi) {
    const int row = m0 + wm * 64 + mi * 16 + lr4;
#pragma unroll
    for (int ni = 0; ni < 4; ++ni) {
      const int col = n0 + wn * 64 + ni * 16 + l15;
      const float bi = bias[col];
#pragma unroll
      for (int j = 0; j < 4; ++j)
        out[(size_t)(row + j) * TD + col] = acc[mi][ni][j] + bi;
    }
  }
}

extern "C" void kernel_launch(void* const* d_in, const int* in_sizes, int n_in,
                              void* d_out, int out_size, void* d_ws, size_t ws_size,
                              hipStream_t stream) {
  const float* x = (const float*)d_in[0];
  const float* c_attn_w = (const float*)d_in[1];
  const float* c_attn_b = (const float*)d_in[2];
  const float* c_proj_w = (const float*)d_in[3];
  const float* c_proj_b = (const float*)d_in[4];
  float* out = (float*)d_out;

  const size_t SZ_XB = (size_t)4096 * 1024 * 2;
  const size_t SZ_WAT = (size_t)3072 * 1024 * 2;
  const size_t SZ_WPT = (size_t)1024 * 1024 * 2;
  const size_t SZ_HEAD = (size_t)TB * TH * TS * THS * 2;
  const size_t SZ_ATT = (size_t)4096 * 1024 * 2;
  if (ws_size < SZ_XB + SZ_WAT + SZ_WPT + 3 * SZ_HEAD + SZ_ATT) return;

  char* ws = (char*)d_ws;
  unsigned short* xb = (unsigned short*)ws;   ws += SZ_XB;
  unsigned short* waT = (unsigned short*)ws;  ws += SZ_WAT;
  unsigned short* wpT = (unsigned short*)ws;  ws += SZ_WPT;
  unsigned short* Qb = (unsigned short*)ws;   ws += SZ_HEAD;
  unsigned short* Kb = (unsigned short*)ws;   ws += SZ_HEAD;
  unsigned short* VTb = (unsigned short*)ws;  ws += SZ_HEAD;
  unsigned short* attn = (unsigned short*)ws; ws += SZ_ATT;

  // KV-split partial buffers: reuse xb (dead after gemm_qkv) for O-partials (exactly 8 MB:
  // 1024 (b,h,w) x 2 halves x 32 rows x 64 d bf16) and waT (dead after gemm_qkv) for (m,l).
  unsigned short* pO = xb;
  float2* pML = (float2*)waT;

  k_cvt_bf16x4<<<4096, 256, 0, stream>>>(x, (ushort4*)xb, 4096 * 1024 / 4);
  k_transpose_bf<<<dim3(3072 / 32, 1024 / 32), 256, 0, stream>>>(c_attn_w, waT, 1024, 3072);
  k_transpose_bf<<<dim3(1024 / 32, 1024 / 32), 256, 0, stream>>>(c_proj_w, wpT, 1024, 1024);
  k_gemm_qkv<<<dim3(3072 / 128, 4096 / 128), 256, 0, stream>>>(xb, waT, c_attn_b, Qb, Kb, VTb);
  k_attn<<<dim3(24, TH, TB), 256, 0, stream>>>(Qb, Kb, VTb, attn, pO, pML);
  k_attn_combine<<<dim3(32, TH, TB), 64, 0, stream>>>(pO, pML, attn);
  k_gemm_proj<<<dim3(1024 / 128, 4096 / 128), 256, 0, stream>>>(attn, wpT, c_proj_b, out);
}

// Round 9
// 221.796 us; speedup vs baseline: 1.1116x; 1.1116x over previous
//
#include <hip/hip_runtime.h>
#include <hip/hip_bf16.h>
#include <stdint.h>

#define TB 2
#define TS 2048
#define TD 1024
#define TH 16
#define THS 64
#define TK 1024  // inner dim of both GEMMs

typedef __attribute__((ext_vector_type(8))) short short8;
typedef __attribute__((ext_vector_type(4))) short short4v;
typedef __attribute__((ext_vector_type(4))) float f32x4;
typedef __attribute__((ext_vector_type(16))) float f32x16;
typedef __attribute__((ext_vector_type(4))) unsigned int uint4v;

static __device__ __forceinline__ unsigned short f2bf(float f) {
  union { float f; unsigned u; } v; v.f = f;
  unsigned r = v.u + 0x7FFFu + ((v.u >> 16) & 1u);  // RTNE
  return (unsigned short)(r >> 16);
}

static __device__ __forceinline__ float bf2f(unsigned short u) {
  union { unsigned u; float f; } v; v.u = ((unsigned)u) << 16;
  return v.f;
}

// pack two f32 -> (hi:bf16(b), lo:bf16(a))
static __device__ __forceinline__ unsigned cvtpk(float a, float b) {
  unsigned r;
  asm("v_cvt_pk_bf16_f32 %0, %1, %2" : "=v"(r) : "v"(a), "v"(b));
  return r;
}

// exchange: a.lanes[32:63] <-> b.lanes[0:31]
static __device__ __forceinline__ void swap32(unsigned& a, unsigned& b) {
  asm("v_permlane32_swap_b32 %0, %1" : "+v"(a), "+v"(b));
}

static __device__ __forceinline__ void async_copy16(const void* g, void* l) {
  __builtin_amdgcn_global_load_lds(
      (const __attribute__((address_space(1))) unsigned int*)g,
      (__attribute__((address_space(3))) unsigned int*)l, 16, 0, 0);
}

// ---------------- elementwise fp32 -> bf16 cast ----------------
__global__ __launch_bounds__(256) void k_cvt_bf16x4(const float* __restrict__ in,
                                                    ushort4* __restrict__ out, int n4) {
  int i = blockIdx.x * blockDim.x + threadIdx.x;
  if (i >= n4) return;
  float4 v = ((const float4*)in)[i];
  out[i] = make_ushort4(f2bf(v.x), f2bf(v.y), f2bf(v.z), f2bf(v.w));
}

// ---------------- fp32 [R][C] -> bf16 [C][R] transpose ----------------
__global__ __launch_bounds__(256) void k_transpose_bf(const float* __restrict__ in,
                                                      unsigned short* __restrict__ out,
                                                      int R, int C) {
  __shared__ float tile[32][33];
  const int tx = threadIdx.x & 31, ty = threadIdx.x >> 5;  // ty 0..7
  const int r0 = blockIdx.y * 32, c0 = blockIdx.x * 32;
#pragma unroll
  for (int i = 0; i < 32; i += 8)
    tile[ty + i][tx] = in[(size_t)(r0 + ty + i) * C + c0 + tx];
  __syncthreads();
#pragma unroll
  for (int i = 0; i < 32; i += 8)
    out[(size_t)(c0 + ty + i) * R + r0 + tx] = f2bf(tile[tx][ty + i]);
}

// ---------------- shared GEMM core: C[128x128] tile, K=1024, A[M][K] bf16, BT[N][K] bf16 ----------------
__device__ __forceinline__ void gemm_core_k1024(const unsigned short* __restrict__ A,
                                                const unsigned short* __restrict__ BT,
                                                int m0, int n0,
                                                unsigned short* sA, unsigned short* sB,
                                                f32x4 acc[4][4]) {
  const int tid = threadIdx.x;
  const int wave = tid >> 6, lane = tid & 63;
  const int wm = wave >> 1, wn = wave & 1;

  const unsigned short* gsrc = (wave < 2) ? A : BT;
  const int row0 = (wave < 2) ? m0 : n0;
  unsigned short* lbase = (wave < 2) ? sA : sB;
  const int cw = (wave & 1) * 4;
  const size_t gr = (size_t)(row0 + cw * 16 + (lane >> 2)) * TK + (lane & 3) * 8;

#pragma unroll
  for (int mi = 0; mi < 4; ++mi)
#pragma unroll
    for (int ni = 0; ni < 4; ++ni)
      acc[mi][ni] = (f32x4){0.f, 0.f, 0.f, 0.f};

  auto stage = [&](int buf, int kt) {
    const unsigned short* g = gsrc + gr + kt * 32;
    unsigned short* l = lbase + buf * 4096 + cw * 512;
#pragma unroll
    for (int c = 0; c < 4; ++c)
      async_copy16(g + (size_t)c * 16 * TK, l + c * 512);
  };

  stage(0, 0);
  __syncthreads();

  const int l15 = lane & 15, lk8 = (lane >> 4) * 8;
  const int aoff = (wm * 64 + l15) * 32 + lk8;
  const int boff = (wn * 64 + l15) * 32 + lk8;

  for (int kt = 0; kt < TK / 32; ++kt) {
    const int buf = kt & 1;
    if (kt + 1 < TK / 32) stage(buf ^ 1, kt + 1);
    short8 af[4], bfr[4];
#pragma unroll
    for (int i = 0; i < 4; ++i) {
      af[i] = *(const short8*)&sA[buf * 4096 + aoff + i * 16 * 32];
      bfr[i] = *(const short8*)&sB[buf * 4096 + boff + i * 16 * 32];
    }
#pragma unroll
    for (int mi = 0; mi < 4; ++mi)
#pragma unroll
      for (int ni = 0; ni < 4; ++ni)
        acc[mi][ni] = __builtin_amdgcn_mfma_f32_16x16x32_bf16(af[mi], bfr[ni], acc[mi][ni], 0, 0, 0);
    __syncthreads();
  }
}

// ---------------- GEMM1: qkv = xb @ waT^T + bias -> Q/K [B,H,S,HS] and VT [B,H,HS,S] ----------------
__global__ __launch_bounds__(256) void k_gemm_qkv(const unsigned short* __restrict__ A,
                                                  const unsigned short* __restrict__ BT,
                                                  const float* __restrict__ bias,
                                                  unsigned short* __restrict__ Qo,
                                                  unsigned short* __restrict__ Ko,
                                                  unsigned short* __restrict__ VTo) {
  __shared__ unsigned short smem[4 * 64 * 68];  // 34816 B; front 32 KB doubles as sA/sB
  unsigned short* sA = smem;
  unsigned short* sB = smem + 8192;
  f32x4 acc[4][4];
  const int m0 = blockIdx.y * 128, n0 = blockIdx.x * 128;
  gemm_core_k1024(A, BT, m0, n0, sA, sB, acc);

  const int lane = threadIdx.x & 63, wave = threadIdx.x >> 6;
  const int wm = wave >> 1, wn = wave & 1;
  const int lr4 = (lane >> 4) * 4, l15 = lane & 15;

  const int col0 = n0 + wn * 64;   // 64-aligned -> one head, one region (uniform per wave)
  const int reg = col0 >> 10;      // 0:q 1:k 2:v
  const int h0 = (col0 & 1023) >> 6;
  const bool isV = (reg == 2);
  const int t0 = m0 + wm * 64;     // first row of this wave's subtile
  const int b = t0 >> 11;
  const int s0 = t0 & 2047;

  unsigned short* tw = smem + wave * (64 * 68);
#pragma unroll
  for (int mi = 0; mi < 4; ++mi) {
#pragma unroll
    for (int ni = 0; ni < 4; ++ni) {
      const int c = ni * 16 + l15;
      const float bi = bias[col0 + c];
#pragma unroll
      for (int j = 0; j < 4; ++j) {
        const int r = mi * 16 + lr4 + j;
        tw[isV ? (c * 68 + r) : (r * 68 + c)] = f2bf(acc[mi][ni][j] + bi);
      }
    }
  }
  unsigned short* outp;
  size_t rstride;
  if (isV) {        // row = d, cols = s
    outp = VTo + (((size_t)b * TH + h0) * THS) * TS + s0;
    rstride = TS;
  } else {          // row = s, cols = d
    outp = (reg == 0 ? Qo : Ko) + (((size_t)b * TH + h0) * TS + s0) * THS;
    rstride = THS;
  }
#pragma unroll
  for (int p2 = 0; p2 < 8; ++p2) {
    const int rp = p2 * 8 + (lane >> 3);
    const int co = (lane & 7) * 8;
    union { short4v h[2]; short8 s8; } u;
    u.h[0] = *(const short4v*)&tw[rp * 68 + co];
    u.h[1] = *(const short4v*)&tw[rp * 68 + co + 4];
    *(short8*)(outp + (size_t)rp * rstride + co) = u.s8;
  }
}

// ---------------- flash attention, causal, KV-SPLIT v2 (exact balance) ----------------
// Every q-tile w splits into chains [0,hw) and [hw,w+1), hw = ceil((w+1)/2). Block j
// handles q-tiles j and 63-j: wave lengths sum to EXACTLY 65 for all 1024 blocks; 1024 =
// 4 x 256 CUs -> every CU gets exactly 260 tile-iters regardless of assignment. 4096
// waves (4/SIMD, 2x R2), max chain 32. ALL waves write unnormalized O + (m,l): half0
// into attn (merged in place), half1 into pO (=xb, exact fit); combine normalizes.
// Inner loop math identical to R2+defer (verified).
__global__ __launch_bounds__(256) void k_attn(const unsigned short* __restrict__ Q,
                                              const unsigned short* __restrict__ K,
                                              const unsigned short* __restrict__ VT,
                                              unsigned short* __restrict__ attn,
                                              unsigned short* __restrict__ pO,
                                              float2* __restrict__ pML) {
  __shared__ unsigned short sO[4][32 * 68];  // per-wave O transpose buffer, stride 68
  const int lane = threadIdx.x & 63, wave = threadIdx.x >> 6;
  const int l31 = lane & 31, h = lane >> 5;
  const int j = blockIdx.x;                  // 0..31
  const int hh = blockIdx.y, b = blockIdx.z;

  const int wt = (wave < 2) ? j : 63 - j;    // q-tile this wave works on
  const int hw = (wt + 2) >> 1;              // ceil((wt+1)/2)
  const int half1 = wave & 1;
  const int lo = half1 ? hw : 0;
  const int hi = half1 ? (wt + 1) : hw;      // empty chain possible only for half1, wt=0
  const bool diag = (hi == wt + 1) && (hi > lo);
  const int qrb = wt * 32;

  const unsigned short* Qh = Q + (((size_t)b * TH + hh) * TS) * THS;
  const unsigned short* Kh = K + (((size_t)b * TH + hh) * TS) * THS;
  const unsigned short* Vh = VT + (((size_t)b * TH + hh) * THS) * TS;

  // Q B-frags: lane holds row (qrb + l31), d-chunk c2*16 + h*8
  short8 qf[4];
#pragma unroll
  for (int c2 = 0; c2 < 4; ++c2)
    qf[c2] = *(const short8*)&Qh[(size_t)(qrb + l31) * THS + c2 * 16 + h * 8];

  f32x16 o0 = {}, o1 = {};
  float m_run = -1e30f, l_run = 0.f;
  const float cl2e = 0.125f * 1.44269504088896340736f;  // scale * log2(e)
  const float THR = 8.0f / cl2e;                        // defer-rescale threshold (raw score)

  // K A-frags for first tile of the chain (row lo*32 <= 2047-31, always valid memory)
  short8 kf[4];
#pragma unroll
  for (int c2 = 0; c2 < 4; ++c2)
    kf[c2] = *(const short8*)&Kh[(size_t)(lo * 32 + l31) * THS + c2 * 16 + h * 8];

  for (int kt = lo; kt < hi; ++kt) {
    const int kb = kt * 32;
    // V^T A-frags for current tile (consumed after softmax -> latency-tolerant)
    short8 vf[2][2];
#pragma unroll
    for (int t = 0; t < 2; ++t)
#pragma unroll
      for (int c2 = 0; c2 < 2; ++c2)
        vf[t][c2] = *(const short8*)&Vh[(size_t)(t * 32 + l31) * TS + kb + c2 * 16 + h * 8];

    // S^T[k][q] accumulate over d
    f32x16 s = {};
#pragma unroll
    for (int c2 = 0; c2 < 4; ++c2)
      s = __builtin_amdgcn_mfma_f32_32x32x16_bf16(kf[c2], qf[c2], s, 0, 0, 0);

    // prefetch next K tile (in-place WAR; loads issue after mfma reads)
    if (kt + 1 < hi) {
#pragma unroll
      for (int c2 = 0; c2 < 4; ++c2)
        kf[c2] = *(const short8*)&Kh[(size_t)(kb + 32 + l31) * THS + c2 * 16 + h * 8];
    }

    // causal mask on the diagonal tile
    if (diag && kt == hi - 1) {
#pragma unroll
      for (int r = 0; r < 16; ++r)
        if ((r & 3) + 8 * (r >> 2) + 4 * h > l31) s[r] = -1e30f;
    }

    // online softmax (per-lane q = l31, replicated across halves); tree reductions
    const float ma = fmaxf(fmaxf(s[0], s[1]), fmaxf(s[2], s[3]));
    const float mb = fmaxf(fmaxf(s[4], s[5]), fmaxf(s[6], s[7]));
    const float mc = fmaxf(fmaxf(s[8], s[9]), fmaxf(s[10], s[11]));
    const float md = fmaxf(fmaxf(s[12], s[13]), fmaxf(s[14], s[15]));
    float tm = fmaxf(fmaxf(ma, mb), fmaxf(mc, md));
    tm = fmaxf(tm, __shfl_xor(tm, 32));

    float al;
    if (__all(tm <= m_run + THR)) {
      al = 1.0f;  // defer: keep old max, P bounded by exp2(8)
    } else {
      const float mn = fmaxf(m_run, tm);
      al = __builtin_amdgcn_exp2f((m_run - mn) * cl2e);
      m_run = mn;
      o0 *= al;
      o1 *= al;
    }
#pragma unroll
    for (int r = 0; r < 16; ++r)
      s[r] = __builtin_amdgcn_exp2f((s[r] - m_run) * cl2e);
    const float sa = (s[0] + s[1]) + (s[2] + s[3]);
    const float sb2 = (s[4] + s[5]) + (s[6] + s[7]);
    const float sc = (s[8] + s[9]) + (s[10] + s[11]);
    const float sd = (s[12] + s[13]) + (s[14] + s[15]);
    float ts = (sa + sb2) + (sc + sd);
    ts += __shfl_xor(ts, 32);
    l_run = l_run * al + ts;

    // P^T B-frags: pack pairs to bf16, pairwise permlane32_swap -> frag words in order
    unsigned B0 = cvtpk(s[0], s[1]), B1 = cvtpk(s[2], s[3]);
    unsigned B2 = cvtpk(s[4], s[5]), B3 = cvtpk(s[6], s[7]);
    swap32(B0, B2);
    swap32(B1, B3);
    unsigned B4 = cvtpk(s[8], s[9]), B5 = cvtpk(s[10], s[11]);
    unsigned B6 = cvtpk(s[12], s[13]), B7 = cvtpk(s[14], s[15]);
    swap32(B4, B6);
    swap32(B5, B7);
    union U { uint4v u; short8 s8; } u0, u1;
    u0.u = (uint4v){B0, B1, B2, B3};
    u1.u = (uint4v){B4, B5, B6, B7};

    o0 = __builtin_amdgcn_mfma_f32_32x32x16_bf16(vf[0][0], u0.s8, o0, 0, 0, 0);
    o0 = __builtin_amdgcn_mfma_f32_32x32x16_bf16(vf[0][1], u1.s8, o0, 0, 0, 0);
    o1 = __builtin_amdgcn_mfma_f32_32x32x16_bf16(vf[1][0], u0.s8, o1, 0, 0, 0);
    o1 = __builtin_amdgcn_mfma_f32_32x32x16_bf16(vf[1][1], u1.s8, o1, 0, 0, 0);
  }

  // epilogue: unnormalized O^T -> LDS (wave-private, no barrier) -> coalesced 16B stores
  unsigned* so32 = (unsigned*)&sO[wave][0];
#pragma unroll
  for (int j2 = 0; j2 < 8; ++j2) {
    const int d0 = ((2 * j2) & 3) + 8 * (j2 >> 1) + 4 * h;  // even d of the pair
    so32[l31 * 34 + (d0 >> 1)] = cvtpk(o0[2 * j2], o0[2 * j2 + 1]);
    so32[l31 * 34 + ((32 + d0) >> 1)] = cvtpk(o1[2 * j2], o1[2 * j2 + 1]);
  }
  if (!half1) {  // half0 -> attn (merged in place by combine)
#pragma unroll
    for (int p2 = 0; p2 < 4; ++p2) {
      const int rp = p2 * 8 + (lane >> 3);
      const int co = (lane & 7) * 8;
      union { short4v h[2]; short8 s8; } u;
      u.h[0] = *(const short4v*)&sO[wave][rp * 68 + co];
      u.h[1] = *(const short4v*)&sO[wave][rp * 68 + co + 4];
      *(short8*)(&attn[(size_t)(b * TS + qrb + rp) * TD + hh * THS + co]) = u.s8;
    }
  } else {       // half1 -> pO chunk
    unsigned short* gp0 = pO + ((size_t)((b * TH + hh) * 64 + wt)) * 32 * 64;
#pragma unroll
    for (int p2 = 0; p2 < 4; ++p2) {
      const int rp = p2 * 8 + (lane >> 3);
      const int co = (lane & 7) * 8;
      union { short4v h[2]; short8 s8; } u;
      u.h[0] = *(const short4v*)&sO[wave][rp * 68 + co];
      u.h[1] = *(const short4v*)&sO[wave][rp * 68 + co + 4];
      *(short8*)(gp0 + rp * 64 + co) = u.s8;
    }
  }
  if (h == 0)
    pML[((size_t)((b * TH + hh) * 64 + wt) * 2 + half1) * 32 + l31] =
        make_float2(m_run, l_run);
}

// ---------------- combine the two KV-split halves (all 64 q-tiles, in-place on attn) ----
__global__ __launch_bounds__(64) void k_attn_combine(const unsigned short* __restrict__ pO,
                                                     const float2* __restrict__ pML,
                                                     unsigned short* __restrict__ attn) {
  const int d = threadIdx.x;                 // 0..63
  const int wt = blockIdx.x;                 // q-tile 0..63
  const int hh = blockIdx.y, b = blockIdx.z;
  const int base = (b * TH + hh) * 64 + wt;
  const float cl2e = 0.125f * 1.44269504088896340736f;
  const unsigned short* ob = pO + (size_t)base * 32 * 64;
#pragma unroll 4
  for (int r = 0; r < 32; ++r) {
    const float2 A = pML[((size_t)base * 2 + 0) * 32 + r];
    const float2 Bv = pML[((size_t)base * 2 + 1) * 32 + r];
    const float m = fmaxf(A.x, Bv.x);
    const float eA = __builtin_amdgcn_exp2f((A.x - m) * cl2e);
    const float eB = __builtin_amdgcn_exp2f((Bv.x - m) * cl2e);
    const float linv = 1.0f / (A.y * eA + Bv.y * eB);
    const size_t ai = (size_t)(b * TS + wt * 32 + r) * TD + hh * THS + d;
    const float o = (bf2f(attn[ai]) * eA + bf2f(ob[r * 64 + d]) * eB) * linv;
    attn[ai] = f2bf(o);
  }
}

// ---------------- GEMM2: out = attn @ wpT^T + bias (fp32 out) ----------------
__global__ __launch_bounds__(256) void k_gemm_proj(const unsigned short* __restrict__ A,
                                                   const unsigned short* __restrict__ BT,
                                                   const float* __restrict__ bias,
                                                   float* __restrict__ out) {
  __shared__ unsigned short sA[2 * 4096];
  __shared__ unsigned short sB[2 * 4096];
  f32x4 acc[4][4];
  const int m0 = blockIdx.y * 128, n0 = blockIdx.x * 128;
  gemm_core_k1024(A, BT, m0, n0, sA, sB, acc);

  const int lane = threadIdx.x & 63, wave = threadIdx.x >> 6;
  const int wm = wave >> 1, wn = wave & 1;
  const int lr4 = (lane >> 4) * 4, l15 = lane & 15;
#pragma unroll
  for (int mi = 0; mi < 4; ++mi) {
    const int row = m0 + wm * 64 + mi * 16 + lr4;
#pragma unroll
    for (int ni = 0; ni < 4; ++ni) {
      const int col = n0 + wn * 64 + ni * 16 + l15;
      const float bi = bias[col];
#pragma unroll
      for (int j = 0; j < 4; ++j)
        out[(size_t)(row + j) * TD + col] = acc[mi][ni][j] + bi;
    }
  }
}

extern "C" void kernel_launch(void* const* d_in, const int* in_sizes, int n_in,
                              void* d_out, int out_size, void* d_ws, size_t ws_size,
                              hipStream_t stream) {
  const float* x = (const float*)d_in[0];
  const float* c_attn_w = (const float*)d_in[1];
  const float* c_attn_b = (const float*)d_in[2];
  const float* c_proj_w = (const float*)d_in[3];
  const float* c_proj_b = (const float*)d_in[4];
  float* out = (float*)d_out;

  const size_t SZ_XB = (size_t)4096 * 1024 * 2;
  const size_t SZ_WAT = (size_t)3072 * 1024 * 2;
  const size_t SZ_WPT = (size_t)1024 * 1024 * 2;
  const size_t SZ_HEAD = (size_t)TB * TH * TS * THS * 2;
  const size_t SZ_ATT = (size_t)4096 * 1024 * 2;
  if (ws_size < SZ_XB + SZ_WAT + SZ_WPT + 3 * SZ_HEAD + SZ_ATT) return;

  char* ws = (char*)d_ws;
  unsigned short* xb = (unsigned short*)ws;   ws += SZ_XB;
  unsigned short* waT = (unsigned short*)ws;  ws += SZ_WAT;
  unsigned short* wpT = (unsigned short*)ws;  ws += SZ_WPT;
  unsigned short* Qb = (unsigned short*)ws;   ws += SZ_HEAD;
  unsigned short* Kb = (unsigned short*)ws;   ws += SZ_HEAD;
  unsigned short* VTb = (unsigned short*)ws;  ws += SZ_HEAD;
  unsigned short* attn = (unsigned short*)ws; ws += SZ_ATT;

  // KV-split v2 partial buffers: pO (half1 O, 2048 chunks x 32x64 bf16 = 8.39 MB) reuses
  // xb exactly; pML (2048 chunks x 2 halves x 32 rows float2 = 1 MB) reuses waT. Both are
  // dead after k_gemm_qkv.
  unsigned short* pO = xb;
  float2* pML = (float2*)waT;

  k_cvt_bf16x4<<<4096, 256, 0, stream>>>(x, (ushort4*)xb, 4096 * 1024 / 4);
  k_transpose_bf<<<dim3(3072 / 32, 1024 / 32), 256, 0, stream>>>(c_attn_w, waT, 1024, 3072);
  k_transpose_bf<<<dim3(1024 / 32, 1024 / 32), 256, 0, stream>>>(c_proj_w, wpT, 1024, 1024);
  k_gemm_qkv<<<dim3(3072 / 128, 4096 / 128), 256, 0, stream>>>(xb, waT, c_attn_b, Qb, Kb, VTb);
  k_attn<<<dim3(32, TH, TB), 256, 0, stream>>>(Qb, Kb, VTb, attn, pO, pML);
  k_attn_combine<<<dim3(64, TH, TB), 64, 0, stream>>>(pO, pML, attn);
  k_gemm_proj<<<dim3(1024 / 128, 4096 / 128), 256, 0, stream>>>(attn, wpT, c_proj_b, out);
}

// Round 10
// 219.461 us; speedup vs baseline: 1.1235x; 1.0106x over previous
//
#include <hip/hip_runtime.h>
#include <hip/hip_bf16.h>
#include <stdint.h>

#define TB 2
#define TS 2048
#define TD 1024
#define TH 16
#define THS 64
#define TK 1024  // inner dim of both GEMMs

typedef __attribute__((ext_vector_type(8))) short short8;
typedef __attribute__((ext_vector_type(4))) short short4v;
typedef __attribute__((ext_vector_type(4))) float f32x4;
typedef __attribute__((ext_vector_type(16))) float f32x16;
typedef __attribute__((ext_vector_type(4))) unsigned int uint4v;

static __device__ __forceinline__ unsigned short f2bf(float f) {
  union { float f; unsigned u; } v; v.f = f;
  unsigned r = v.u + 0x7FFFu + ((v.u >> 16) & 1u);  // RTNE
  return (unsigned short)(r >> 16);
}

static __device__ __forceinline__ float bf2f(unsigned short u) {
  union { unsigned u; float f; } v; v.u = ((unsigned)u) << 16;
  return v.f;
}

// pack two f32 -> (hi:bf16(b), lo:bf16(a))
static __device__ __forceinline__ unsigned cvtpk(float a, float b) {
  unsigned r;
  asm("v_cvt_pk_bf16_f32 %0, %1, %2" : "=v"(r) : "v"(a), "v"(b));
  return r;
}

// exchange: a.lanes[32:63] <-> b.lanes[0:31]
static __device__ __forceinline__ void swap32(unsigned& a, unsigned& b) {
  asm("v_permlane32_swap_b32 %0, %1" : "+v"(a), "+v"(b));
}

static __device__ __forceinline__ void async_copy16(const void* g, void* l) {
  __builtin_amdgcn_global_load_lds(
      (const __attribute__((address_space(1))) unsigned int*)g,
      (__attribute__((address_space(3))) unsigned int*)l, 16, 0, 0);
}

// ---------------- elementwise fp32 -> bf16 cast ----------------
__global__ __launch_bounds__(256) void k_cvt_bf16x4(const float* __restrict__ in,
                                                    ushort4* __restrict__ out, int n4) {
  int i = blockIdx.x * blockDim.x + threadIdx.x;
  if (i >= n4) return;
  float4 v = ((const float4*)in)[i];
  out[i] = make_ushort4(f2bf(v.x), f2bf(v.y), f2bf(v.z), f2bf(v.w));
}

// ---------------- fp32 [R][C] -> bf16 [C][R] transpose ----------------
__global__ __launch_bounds__(256) void k_transpose_bf(const float* __restrict__ in,
                                                      unsigned short* __restrict__ out,
                                                      int R, int C) {
  __shared__ float tile[32][33];
  const int tx = threadIdx.x & 31, ty = threadIdx.x >> 5;  // ty 0..7
  const int r0 = blockIdx.y * 32, c0 = blockIdx.x * 32;
#pragma unroll
  for (int i = 0; i < 32; i += 8)
    tile[ty + i][tx] = in[(size_t)(r0 + ty + i) * C + c0 + tx];
  __syncthreads();
#pragma unroll
  for (int i = 0; i < 32; i += 8)
    out[(size_t)(c0 + ty + i) * R + r0 + tx] = f2bf(tile[tx][ty + i]);
}

// ---------------- shared GEMM core: C[128x128] tile, K=1024, A[M][K] bf16, BT[N][K] bf16 ----------------
__device__ __forceinline__ void gemm_core_k1024(const unsigned short* __restrict__ A,
                                                const unsigned short* __restrict__ BT,
                                                int m0, int n0,
                                                unsigned short* sA, unsigned short* sB,
                                                f32x4 acc[4][4]) {
  const int tid = threadIdx.x;
  const int wave = tid >> 6, lane = tid & 63;
  const int wm = wave >> 1, wn = wave & 1;

  const unsigned short* gsrc = (wave < 2) ? A : BT;
  const int row0 = (wave < 2) ? m0 : n0;
  unsigned short* lbase = (wave < 2) ? sA : sB;
  const int cw = (wave & 1) * 4;
  const size_t gr = (size_t)(row0 + cw * 16 + (lane >> 2)) * TK + (lane & 3) * 8;

#pragma unroll
  for (int mi = 0; mi < 4; ++mi)
#pragma unroll
    for (int ni = 0; ni < 4; ++ni)
      acc[mi][ni] = (f32x4){0.f, 0.f, 0.f, 0.f};

  auto stage = [&](int buf, int kt) {
    const unsigned short* g = gsrc + gr + kt * 32;
    unsigned short* l = lbase + buf * 4096 + cw * 512;
#pragma unroll
    for (int c = 0; c < 4; ++c)
      async_copy16(g + (size_t)c * 16 * TK, l + c * 512);
  };

  stage(0, 0);
  __syncthreads();

  const int l15 = lane & 15, lk8 = (lane >> 4) * 8;
  const int aoff = (wm * 64 + l15) * 32 + lk8;
  const int boff = (wn * 64 + l15) * 32 + lk8;

  for (int kt = 0; kt < TK / 32; ++kt) {
    const int buf = kt & 1;
    if (kt + 1 < TK / 32) stage(buf ^ 1, kt + 1);
    short8 af[4], bfr[4];
#pragma unroll
    for (int i = 0; i < 4; ++i) {
      af[i] = *(const short8*)&sA[buf * 4096 + aoff + i * 16 * 32];
      bfr[i] = *(const short8*)&sB[buf * 4096 + boff + i * 16 * 32];
    }
#pragma unroll
    for (int mi = 0; mi < 4; ++mi)
#pragma unroll
      for (int ni = 0; ni < 4; ++ni)
        acc[mi][ni] = __builtin_amdgcn_mfma_f32_16x16x32_bf16(af[mi], bfr[ni], acc[mi][ni], 0, 0, 0);
    __syncthreads();
  }
}

// ---------------- GEMM1: qkv = xb @ waT^T + bias -> Q/K [B,H,S,HS] and VT [B,H,HS,S] ----------------
__global__ __launch_bounds__(256) void k_gemm_qkv(const unsigned short* __restrict__ A,
                                                  const unsigned short* __restrict__ BT,
                                                  const float* __restrict__ bias,
                                                  unsigned short* __restrict__ Qo,
                                                  unsigned short* __restrict__ Ko,
                                                  unsigned short* __restrict__ VTo) {
  __shared__ unsigned short smem[4 * 64 * 68];  // 34816 B; front 32 KB doubles as sA/sB
  unsigned short* sA = smem;
  unsigned short* sB = smem + 8192;
  f32x4 acc[4][4];
  const int m0 = blockIdx.y * 128, n0 = blockIdx.x * 128;
  gemm_core_k1024(A, BT, m0, n0, sA, sB, acc);

  const int lane = threadIdx.x & 63, wave = threadIdx.x >> 6;
  const int wm = wave >> 1, wn = wave & 1;
  const int lr4 = (lane >> 4) * 4, l15 = lane & 15;

  const int col0 = n0 + wn * 64;   // 64-aligned -> one head, one region (uniform per wave)
  const int reg = col0 >> 10;      // 0:q 1:k 2:v
  const int h0 = (col0 & 1023) >> 6;
  const bool isV = (reg == 2);
  const int t0 = m0 + wm * 64;     // first row of this wave's subtile
  const int b = t0 >> 11;
  const int s0 = t0 & 2047;

  unsigned short* tw = smem + wave * (64 * 68);
#pragma unroll
  for (int mi = 0; mi < 4; ++mi) {
#pragma unroll
    for (int ni = 0; ni < 4; ++ni) {
      const int c = ni * 16 + l15;
      const float bi = bias[col0 + c];
#pragma unroll
      for (int j = 0; j < 4; ++j) {
        const int r = mi * 16 + lr4 + j;
        tw[isV ? (c * 68 + r) : (r * 68 + c)] = f2bf(acc[mi][ni][j] + bi);
      }
    }
  }
  unsigned short* outp;
  size_t rstride;
  if (isV) {        // row = d, cols = s
    outp = VTo + (((size_t)b * TH + h0) * THS) * TS + s0;
    rstride = TS;
  } else {          // row = s, cols = d
    outp = (reg == 0 ? Qo : Ko) + (((size_t)b * TH + h0) * TS + s0) * THS;
    rstride = THS;
  }
#pragma unroll
  for (int p2 = 0; p2 < 8; ++p2) {
    const int rp = p2 * 8 + (lane >> 3);
    const int co = (lane & 7) * 8;
    union { short4v h[2]; short8 s8; } u;
    u.h[0] = *(const short4v*)&tw[rp * 68 + co];
    u.h[1] = *(const short4v*)&tw[rp * 68 + co + 4];
    *(short8*)(outp + (size_t)rp * rstride + co) = u.s8;
  }
}

// ---------------- flash attention, causal, KV-SPLIT v2 + XCD-pinned heads ----------------
// v2 split (R9): every q-tile w -> chains [0,hw) and [hw,w+1), hw=ceil((w+1)/2); block j
// holds q-tiles {j, 63-j} -> EXACTLY 65 tile-iters per block, so load balance is
// placement-independent. NEW (this round): block lin -> (xcd = lin&7) owns 4 (b,h) pairs
// (K+V = 2 MB < 4 MB L2/XCD, R3-proven mapping) x 32 equal blocks -> K/V L2-resident.
// Inner loop math identical to R9 (verified).
__global__ __launch_bounds__(256) void k_attn(const unsigned short* __restrict__ Q,
                                              const unsigned short* __restrict__ K,
                                              const unsigned short* __restrict__ VT,
                                              unsigned short* __restrict__ attn,
                                              unsigned short* __restrict__ pO,
                                              float2* __restrict__ pML) {
  __shared__ unsigned short sO[4][32 * 68];  // per-wave O transpose buffer, stride 68
  const int lane = threadIdx.x & 63, wave = threadIdx.x >> 6;
  const int l31 = lane & 31, h = lane >> 5;

  const int lin = blockIdx.x;                // 1024 blocks, all equal length
  const int xcd = lin & 7;                   // XCD-group (m09/R3-verified %8 heuristic)
  const int r2 = lin >> 3;                   // 0..127 within XCD-group
  const int pair = xcd * 4 + (r2 >> 5);      // 4 (b,h) pairs per XCD
  const int j = r2 & 31;                     // 0..31
  const int b = pair >> 4, hh = pair & 15;

  const int wt = (wave < 2) ? j : 63 - j;    // q-tile this wave works on
  const int hw = (wt + 2) >> 1;              // ceil((wt+1)/2)
  const int half1 = wave & 1;
  const int lo = half1 ? hw : 0;
  const int hi = half1 ? (wt + 1) : hw;      // empty chain possible only for half1, wt=0
  const bool diag = (hi == wt + 1) && (hi > lo);
  const int qrb = wt * 32;

  const unsigned short* Qh = Q + (((size_t)b * TH + hh) * TS) * THS;
  const unsigned short* Kh = K + (((size_t)b * TH + hh) * TS) * THS;
  const unsigned short* Vh = VT + (((size_t)b * TH + hh) * THS) * TS;

  // Q B-frags: lane holds row (qrb + l31), d-chunk c2*16 + h*8
  short8 qf[4];
#pragma unroll
  for (int c2 = 0; c2 < 4; ++c2)
    qf[c2] = *(const short8*)&Qh[(size_t)(qrb + l31) * THS + c2 * 16 + h * 8];

  f32x16 o0 = {}, o1 = {};
  float m_run = -1e30f, l_run = 0.f;
  const float cl2e = 0.125f * 1.44269504088896340736f;  // scale * log2(e)
  const float THR = 8.0f / cl2e;                        // defer-rescale threshold (raw score)

  // K A-frags for first tile of the chain
  short8 kf[4];
#pragma unroll
  for (int c2 = 0; c2 < 4; ++c2)
    kf[c2] = *(const short8*)&Kh[(size_t)(lo * 32 + l31) * THS + c2 * 16 + h * 8];

  for (int kt = lo; kt < hi; ++kt) {
    const int kb = kt * 32;
    // V^T A-frags for current tile (consumed after softmax -> latency-tolerant)
    short8 vf[2][2];
#pragma unroll
    for (int t = 0; t < 2; ++t)
#pragma unroll
      for (int c2 = 0; c2 < 2; ++c2)
        vf[t][c2] = *(const short8*)&Vh[(size_t)(t * 32 + l31) * TS + kb + c2 * 16 + h * 8];

    // S^T[k][q] accumulate over d
    f32x16 s = {};
#pragma unroll
    for (int c2 = 0; c2 < 4; ++c2)
      s = __builtin_amdgcn_mfma_f32_32x32x16_bf16(kf[c2], qf[c2], s, 0, 0, 0);

    // prefetch next K tile (in-place WAR; loads issue after mfma reads)
    if (kt + 1 < hi) {
#pragma unroll
      for (int c2 = 0; c2 < 4; ++c2)
        kf[c2] = *(const short8*)&Kh[(size_t)(kb + 32 + l31) * THS + c2 * 16 + h * 8];
    }

    // causal mask on the diagonal tile
    if (diag && kt == hi - 1) {
#pragma unroll
      for (int r = 0; r < 16; ++r)
        if ((r & 3) + 8 * (r >> 2) + 4 * h > l31) s[r] = -1e30f;
    }

    // online softmax (per-lane q = l31, replicated across halves); tree reductions
    const float ma = fmaxf(fmaxf(s[0], s[1]), fmaxf(s[2], s[3]));
    const float mb = fmaxf(fmaxf(s[4], s[5]), fmaxf(s[6], s[7]));
    const float mc = fmaxf(fmaxf(s[8], s[9]), fmaxf(s[10], s[11]));
    const float md = fmaxf(fmaxf(s[12], s[13]), fmaxf(s[14], s[15]));
    float tm = fmaxf(fmaxf(ma, mb), fmaxf(mc, md));
    tm = fmaxf(tm, __shfl_xor(tm, 32));

    float al;
    if (__all(tm <= m_run + THR)) {
      al = 1.0f;  // defer: keep old max, P bounded by exp2(8)
    } else {
      const float mn = fmaxf(m_run, tm);
      al = __builtin_amdgcn_exp2f((m_run - mn) * cl2e);
      m_run = mn;
      o0 *= al;
      o1 *= al;
    }
#pragma unroll
    for (int r = 0; r < 16; ++r)
      s[r] = __builtin_amdgcn_exp2f((s[r] - m_run) * cl2e);
    const float sa = (s[0] + s[1]) + (s[2] + s[3]);
    const float sb2 = (s[4] + s[5]) + (s[6] + s[7]);
    const float sc = (s[8] + s[9]) + (s[10] + s[11]);
    const float sd = (s[12] + s[13]) + (s[14] + s[15]);
    float ts = (sa + sb2) + (sc + sd);
    ts += __shfl_xor(ts, 32);
    l_run = l_run * al + ts;

    // P^T B-frags: pack pairs to bf16, pairwise permlane32_swap -> frag words in order
    unsigned B0 = cvtpk(s[0], s[1]), B1 = cvtpk(s[2], s[3]);
    unsigned B2 = cvtpk(s[4], s[5]), B3 = cvtpk(s[6], s[7]);
    swap32(B0, B2);
    swap32(B1, B3);
    unsigned B4 = cvtpk(s[8], s[9]), B5 = cvtpk(s[10], s[11]);
    unsigned B6 = cvtpk(s[12], s[13]), B7 = cvtpk(s[14], s[15]);
    swap32(B4, B6);
    swap32(B5, B7);
    union U { uint4v u; short8 s8; } u0, u1;
    u0.u = (uint4v){B0, B1, B2, B3};
    u1.u = (uint4v){B4, B5, B6, B7};

    o0 = __builtin_amdgcn_mfma_f32_32x32x16_bf16(vf[0][0], u0.s8, o0, 0, 0, 0);
    o0 = __builtin_amdgcn_mfma_f32_32x32x16_bf16(vf[0][1], u1.s8, o0, 0, 0, 0);
    o1 = __builtin_amdgcn_mfma_f32_32x32x16_bf16(vf[1][0], u0.s8, o1, 0, 0, 0);
    o1 = __builtin_amdgcn_mfma_f32_32x32x16_bf16(vf[1][1], u1.s8, o1, 0, 0, 0);
  }

  // epilogue: unnormalized O^T -> LDS (wave-private, no barrier) -> coalesced 16B stores
  unsigned* so32 = (unsigned*)&sO[wave][0];
#pragma unroll
  for (int j2 = 0; j2 < 8; ++j2) {
    const int d0 = ((2 * j2) & 3) + 8 * (j2 >> 1) + 4 * h;  // even d of the pair
    so32[l31 * 34 + (d0 >> 1)] = cvtpk(o0[2 * j2], o0[2 * j2 + 1]);
    so32[l31 * 34 + ((32 + d0) >> 1)] = cvtpk(o1[2 * j2], o1[2 * j2 + 1]);
  }
  if (!half1) {  // half0 -> attn (merged in place by combine)
#pragma unroll
    for (int p2 = 0; p2 < 4; ++p2) {
      const int rp = p2 * 8 + (lane >> 3);
      const int co = (lane & 7) * 8;
      union { short4v h[2]; short8 s8; } u;
      u.h[0] = *(const short4v*)&sO[wave][rp * 68 + co];
      u.h[1] = *(const short4v*)&sO[wave][rp * 68 + co + 4];
      *(short8*)(&attn[(size_t)(b * TS + qrb + rp) * TD + hh * THS + co]) = u.s8;
    }
  } else {       // half1 -> pO chunk
    unsigned short* gp0 = pO + ((size_t)((b * TH + hh) * 64 + wt)) * 32 * 64;
#pragma unroll
    for (int p2 = 0; p2 < 4; ++p2) {
      const int rp = p2 * 8 + (lane >> 3);
      const int co = (lane & 7) * 8;
      union { short4v h[2]; short8 s8; } u;
      u.h[0] = *(const short4v*)&sO[wave][rp * 68 + co];
      u.h[1] = *(const short4v*)&sO[wave][rp * 68 + co + 4];
      *(short8*)(gp0 + rp * 64 + co) = u.s8;
    }
  }
  if (h == 0)
    pML[((size_t)((b * TH + hh) * 64 + wt) * 2 + half1) * 32 + l31] =
        make_float2(m_run, l_run);
}

// ---------------- combine the two KV-split halves (all 64 q-tiles, in-place on attn) ----
__global__ __launch_bounds__(64) void k_attn_combine(const unsigned short* __restrict__ pO,
                                                     const float2* __restrict__ pML,
                                                     unsigned short* __restrict__ attn) {
  const int d = threadIdx.x;                 // 0..63
  const int wt = blockIdx.x;                 // q-tile 0..63
  const int hh = blockIdx.y, b = blockIdx.z;
  const int base = (b * TH + hh) * 64 + wt;
  const float cl2e = 0.125f * 1.44269504088896340736f;
  const unsigned short* ob = pO + (size_t)base * 32 * 64;
#pragma unroll 4
  for (int r = 0; r < 32; ++r) {
    const float2 A = pML[((size_t)base * 2 + 0) * 32 + r];
    const float2 Bv = pML[((size_t)base * 2 + 1) * 32 + r];
    const float m = fmaxf(A.x, Bv.x);
    const float eA = __builtin_amdgcn_exp2f((A.x - m) * cl2e);
    const float eB = __builtin_amdgcn_exp2f((Bv.x - m) * cl2e);
    const float linv = 1.0f / (A.y * eA + Bv.y * eB);
    const size_t ai = (size_t)(b * TS + wt * 32 + r) * TD + hh * THS + d;
    const float o = (bf2f(attn[ai]) * eA + bf2f(ob[r * 64 + d]) * eB) * linv;
    attn[ai] = f2bf(o);
  }
}

// ---------------- GEMM2: out = attn @ wpT^T + bias (fp32 out) ----------------
__global__ __launch_bounds__(256) void k_gemm_proj(const unsigned short* __restrict__ A,
                                                   const unsigned short* __restrict__ BT,
                                                   const float* __restrict__ bias,
                                                   float* __restrict__ out) {
  __shared__ unsigned short sA[2 * 4096];
  __shared__ unsigned short sB[2 * 4096];
  f32x4 acc[4][4];
  const int m0 = blockIdx.y * 128, n0 = blockIdx.x * 128;
  gemm_core_k1024(A, BT, m0, n0, sA, sB, acc);

  const int lane = threadIdx.x & 63, wave = threadIdx.x >> 6;
  const int wm = wave >> 1, wn = wave & 1;
  const int lr4 = (lane >> 4) * 4, l15 = lane & 15;
#pragma unroll
  for (int mi = 0; mi < 4; ++mi) {
    const int row = m0 + wm * 64 + mi * 16 + lr4;
#pragma unroll
    for (int ni = 0; ni < 4; ++ni) {
      const int col = n0 + wn * 64 + ni * 16 + l15;
      const float bi = bias[col];
#pragma unroll
      for (int j = 0; j < 4; ++j)
        out[(size_t)(row + j) * TD + col] = acc[mi][ni][j] + bi;
    }
  }
}

extern "C" void kernel_launch(void* const* d_in, const int* in_sizes, int n_in,
                              void* d_out, int out_size, void* d_ws, size_t ws_size,
                              hipStream_t stream) {
  const float* x = (const float*)d_in[0];
  const float* c_attn_w = (const float*)d_in[1];
  const float* c_attn_b = (const float*)d_in[2];
  const float* c_proj_w = (const float*)d_in[3];
  const float* c_proj_b = (const float*)d_in[4];
  float* out = (float*)d_out;

  const size_t SZ_XB = (size_t)4096 * 1024 * 2;
  const size_t SZ_WAT = (size_t)3072 * 1024 * 2;
  const size_t SZ_WPT = (size_t)1024 * 1024 * 2;
  const size_t SZ_HEAD = (size_t)TB * TH * TS * THS * 2;
  const size_t SZ_ATT = (size_t)4096 * 1024 * 2;
  if (ws_size < SZ_XB + SZ_WAT + SZ_WPT + 3 * SZ_HEAD + SZ_ATT) return;

  char* ws = (char*)d_ws;
  unsigned short* xb = (unsigned short*)ws;   ws += SZ_XB;
  unsigned short* waT = (unsigned short*)ws;  ws += SZ_WAT;
  unsigned short* wpT = (unsigned short*)ws;  ws += SZ_WPT;
  unsigned short* Qb = (unsigned short*)ws;   ws += SZ_HEAD;
  unsigned short* Kb = (unsigned short*)ws;   ws += SZ_HEAD;
  unsigned short* VTb = (unsigned short*)ws;  ws += SZ_HEAD;
  unsigned short* attn = (unsigned short*)ws; ws += SZ_ATT;

  // KV-split v2 partial buffers: pO (half1 O, 2048 chunks x 32x64 bf16 = 8.39 MB) reuses
  // xb exactly; pML (2048 chunks x 2 halves x 32 rows float2 = 1 MB) reuses waT. Both are
  // dead after k_gemm_qkv.
  unsigned short* pO = xb;
  float2* pML = (float2*)waT;

  k_cvt_bf16x4<<<4096, 256, 0, stream>>>(x, (ushort4*)xb, 4096 * 1024 / 4);
  k_transpose_bf<<<dim3(3072 / 32, 1024 / 32), 256, 0, stream>>>(c_attn_w, waT, 1024, 3072);
  k_transpose_bf<<<dim3(1024 / 32, 1024 / 32), 256, 0, stream>>>(c_proj_w, wpT, 1024, 1024);
  k_gemm_qkv<<<dim3(3072 / 128, 4096 / 128), 256, 0, stream>>>(xb, waT, c_attn_b, Qb, Kb, VTb);
  k_attn<<<dim3(1024), 256, 0, stream>>>(Qb, Kb, VTb, attn, pO, pML);
  k_attn_combine<<<dim3(64, TH, TB), 64, 0, stream>>>(pO, pML, attn);
  k_gemm_proj<<<dim3(1024 / 128, 4096 / 128), 256, 0, stream>>>(attn, wpT, c_proj_b, out);
}

// Round 11
// 203.416 us; speedup vs baseline: 1.2121x; 1.0789x over previous
//
#include <hip/hip_runtime.h>
#include <hip/hip_bf16.h>
#include <stdint.h>

#define TB 2
#define TS 2048
#define TD 1024
#define TH 16
#define THS 64
#define TK 1024  // inner dim of both GEMMs

typedef __attribute__((ext_vector_type(8))) short short8;
typedef __attribute__((ext_vector_type(4))) short short4v;
typedef __attribute__((ext_vector_type(4))) float f32x4;
typedef __attribute__((ext_vector_type(16))) float f32x16;
typedef __attribute__((ext_vector_type(4))) unsigned int uint4v;

static __device__ __forceinline__ unsigned short f2bf(float f) {
  union { float f; unsigned u; } v; v.f = f;
  unsigned r = v.u + 0x7FFFu + ((v.u >> 16) & 1u);  // RTNE
  return (unsigned short)(r >> 16);
}

// pack two f32 -> (hi:bf16(b), lo:bf16(a))
static __device__ __forceinline__ unsigned cvtpk(float a, float b) {
  unsigned r;
  asm("v_cvt_pk_bf16_f32 %0, %1, %2" : "=v"(r) : "v"(a), "v"(b));
  return r;
}

// exchange: a.lanes[32:63] <-> b.lanes[0:31]
static __device__ __forceinline__ void swap32(unsigned& a, unsigned& b) {
  asm("v_permlane32_swap_b32 %0, %1" : "+v"(a), "+v"(b));
}

static __device__ __forceinline__ void async_copy16(const void* g, void* l) {
  __builtin_amdgcn_global_load_lds(
      (const __attribute__((address_space(1))) unsigned int*)g,
      (__attribute__((address_space(3))) unsigned int*)l, 16, 0, 0);
}

// ---------------- elementwise fp32 -> bf16 cast ----------------
__global__ __launch_bounds__(256) void k_cvt_bf16x4(const float* __restrict__ in,
                                                    ushort4* __restrict__ out, int n4) {
  int i = blockIdx.x * blockDim.x + threadIdx.x;
  if (i >= n4) return;
  float4 v = ((const float4*)in)[i];
  out[i] = make_ushort4(f2bf(v.x), f2bf(v.y), f2bf(v.z), f2bf(v.w));
}

// ---------------- fp32 [R][C] -> bf16 [C][R] transpose ----------------
__global__ __launch_bounds__(256) void k_transpose_bf(const float* __restrict__ in,
                                                      unsigned short* __restrict__ out,
                                                      int R, int C) {
  __shared__ float tile[32][33];
  const int tx = threadIdx.x & 31, ty = threadIdx.x >> 5;  // ty 0..7
  const int r0 = blockIdx.y * 32, c0 = blockIdx.x * 32;
#pragma unroll
  for (int i = 0; i < 32; i += 8)
    tile[ty + i][tx] = in[(size_t)(r0 + ty + i) * C + c0 + tx];
  __syncthreads();
#pragma unroll
  for (int i = 0; i < 32; i += 8)
    out[(size_t)(c0 + ty + i) * R + r0 + tx] = f2bf(tile[tx][ty + i]);
}

// ---------------- shared GEMM core: C[128x128] tile, K=1024, A[M][K] bf16, BT[N][K] bf16 ----------------
__device__ __forceinline__ void gemm_core_k1024(const unsigned short* __restrict__ A,
                                                const unsigned short* __restrict__ BT,
                                                int m0, int n0,
                                                unsigned short* sA, unsigned short* sB,
                                                f32x4 acc[4][4]) {
  const int tid = threadIdx.x;
  const int wave = tid >> 6, lane = tid & 63;
  const int wm = wave >> 1, wn = wave & 1;

  const unsigned short* gsrc = (wave < 2) ? A : BT;
  const int row0 = (wave < 2) ? m0 : n0;
  unsigned short* lbase = (wave < 2) ? sA : sB;
  const int cw = (wave & 1) * 4;
  const size_t gr = (size_t)(row0 + cw * 16 + (lane >> 2)) * TK + (lane & 3) * 8;

#pragma unroll
  for (int mi = 0; mi < 4; ++mi)
#pragma unroll
    for (int ni = 0; ni < 4; ++ni)
      acc[mi][ni] = (f32x4){0.f, 0.f, 0.f, 0.f};

  auto stage = [&](int buf, int kt) {
    const unsigned short* g = gsrc + gr + kt * 32;
    unsigned short* l = lbase + buf * 4096 + cw * 512;
#pragma unroll
    for (int c = 0; c < 4; ++c)
      async_copy16(g + (size_t)c * 16 * TK, l + c * 512);
  };

  stage(0, 0);
  __syncthreads();

  const int l15 = lane & 15, lk8 = (lane >> 4) * 8;
  const int aoff = (wm * 64 + l15) * 32 + lk8;
  const int boff = (wn * 64 + l15) * 32 + lk8;

  for (int kt = 0; kt < TK / 32; ++kt) {
    const int buf = kt & 1;
    if (kt + 1 < TK / 32) stage(buf ^ 1, kt + 1);
    short8 af[4], bfr[4];
#pragma unroll
    for (int i = 0; i < 4; ++i) {
      af[i] = *(const short8*)&sA[buf * 4096 + aoff + i * 16 * 32];
      bfr[i] = *(const short8*)&sB[buf * 4096 + boff + i * 16 * 32];
    }
#pragma unroll
    for (int mi = 0; mi < 4; ++mi)
#pragma unroll
      for (int ni = 0; ni < 4; ++ni)
        acc[mi][ni] = __builtin_amdgcn_mfma_f32_16x16x32_bf16(af[mi], bfr[ni], acc[mi][ni], 0, 0, 0);
    __syncthreads();
  }
}

// ---------------- GEMM1: qkv = xb @ waT^T + bias -> Q/K [B,H,S,HS] and VT [B,H,HS,S] ----------------
__global__ __launch_bounds__(256) void k_gemm_qkv(const unsigned short* __restrict__ A,
                                                  const unsigned short* __restrict__ BT,
                                                  const float* __restrict__ bias,
                                                  unsigned short* __restrict__ Qo,
                                                  unsigned short* __restrict__ Ko,
                                                  unsigned short* __restrict__ VTo) {
  __shared__ unsigned short smem[4 * 64 * 68];  // 34816 B; front 32 KB doubles as sA/sB
  unsigned short* sA = smem;
  unsigned short* sB = smem + 8192;
  f32x4 acc[4][4];
  const int m0 = blockIdx.y * 128, n0 = blockIdx.x * 128;
  gemm_core_k1024(A, BT, m0, n0, sA, sB, acc);

  const int lane = threadIdx.x & 63, wave = threadIdx.x >> 6;
  const int wm = wave >> 1, wn = wave & 1;
  const int lr4 = (lane >> 4) * 4, l15 = lane & 15;

  const int col0 = n0 + wn * 64;   // 64-aligned -> one head, one region (uniform per wave)
  const int reg = col0 >> 10;      // 0:q 1:k 2:v
  const int h0 = (col0 & 1023) >> 6;
  const bool isV = (reg == 2);
  const int t0 = m0 + wm * 64;     // first row of this wave's subtile
  const int b = t0 >> 11;
  const int s0 = t0 & 2047;

  unsigned short* tw = smem + wave * (64 * 68);
#pragma unroll
  for (int mi = 0; mi < 4; ++mi) {
#pragma unroll
    for (int ni = 0; ni < 4; ++ni) {
      const int c = ni * 16 + l15;
      const float bi = bias[col0 + c];
#pragma unroll
      for (int j = 0; j < 4; ++j) {
        const int r = mi * 16 + lr4 + j;
        tw[isV ? (c * 68 + r) : (r * 68 + c)] = f2bf(acc[mi][ni][j] + bi);
      }
    }
  }
  unsigned short* outp;
  size_t rstride;
  if (isV) {        // row = d, cols = s
    outp = VTo + (((size_t)b * TH + h0) * THS) * TS + s0;
    rstride = TS;
  } else {          // row = s, cols = d
    outp = (reg == 0 ? Qo : Ko) + (((size_t)b * TH + h0) * TS + s0) * THS;
    rstride = THS;
  }
#pragma unroll
  for (int p2 = 0; p2 < 8; ++p2) {
    const int rp = p2 * 8 + (lane >> 3);
    const int co = (lane & 7) * 8;
    union { short4v h[2]; short8 s8; } u;
    u.h[0] = *(const short4v*)&tw[rp * 68 + co];
    u.h[1] = *(const short4v*)&tw[rp * 68 + co + 4];
    *(short8*)(outp + (size_t)rp * rstride + co) = u.s8;
  }
}

// ---------------- flash attention, causal, swapped-operand in-register softmax ----------------
// EXACT R2/R6 kernel (best measured: 68.1 us, twice). 1 block = 4 waves, each wave owns
// 32 q-rows, KVBLK=32, 32x32x16 MFMA, barrier-free independent waves, b-complement balance.
// Attention plateau accepted: R3/R4/R5/R9/R10 variants (locality/LDS/KV-split) all 68-118us;
// chain-bound at ~2650cy/tile-iter regardless of occupancy or FETCH (R10: 12MB, still 72us).
__global__ __launch_bounds__(256) void k_attn(const unsigned short* __restrict__ Q,
                                              const unsigned short* __restrict__ K,
                                              const unsigned short* __restrict__ VT,
                                              unsigned short* __restrict__ attn) {
  __shared__ unsigned short sO[4][32 * 68];  // per-wave O transpose buffer, stride 68
  const int lane = threadIdx.x & 63, wave = threadIdx.x >> 6;
  const int l31 = lane & 31, h = lane >> 5;
  int qt = blockIdx.x;
  const int hh = blockIdx.y, b = blockIdx.z;
  if (b) qt = 15 - qt;  // complement pairing balances the causal triangle across CUs
  const int qrb = qt * 128 + wave * 32;

  const unsigned short* Qh = Q + (((size_t)b * TH + hh) * TS) * THS;
  const unsigned short* Kh = K + (((size_t)b * TH + hh) * TS) * THS;
  const unsigned short* Vh = VT + (((size_t)b * TH + hh) * THS) * TS;

  short8 qf[4];
#pragma unroll
  for (int c2 = 0; c2 < 4; ++c2)
    qf[c2] = *(const short8*)&Qh[(size_t)(qrb + l31) * THS + c2 * 16 + h * 8];

  f32x16 o0 = {}, o1 = {};
  float m_run = -1e30f, l_run = 0.f;
  const float cl2e = 0.125f * 1.44269504088896340736f;  // scale * log2(e)

  const int nkt = (qrb >> 5) + 1;

  short8 kf[4];
#pragma unroll
  for (int c2 = 0; c2 < 4; ++c2)
    kf[c2] = *(const short8*)&Kh[(size_t)l31 * THS + c2 * 16 + h * 8];

  for (int kt = 0; kt < nkt; ++kt) {
    const int kb = kt * 32;
    short8 vf[2][2];
#pragma unroll
    for (int t = 0; t < 2; ++t)
#pragma unroll
      for (int c2 = 0; c2 < 2; ++c2)
        vf[t][c2] = *(const short8*)&Vh[(size_t)(t * 32 + l31) * TS + kb + c2 * 16 + h * 8];

    f32x16 s = {};
#pragma unroll
    for (int c2 = 0; c2 < 4; ++c2)
      s = __builtin_amdgcn_mfma_f32_32x32x16_bf16(kf[c2], qf[c2], s, 0, 0, 0);

    if (kt + 1 < nkt) {
#pragma unroll
      for (int c2 = 0; c2 < 4; ++c2)
        kf[c2] = *(const short8*)&Kh[(size_t)(kb + 32 + l31) * THS + c2 * 16 + h * 8];
    }

    if (kt == nkt - 1) {
#pragma unroll
      for (int r = 0; r < 16; ++r)
        if ((r & 3) + 8 * (r >> 2) + 4 * h > l31) s[r] = -1e30f;
    }

    float tm = s[0];
#pragma unroll
    for (int r = 1; r < 16; ++r) tm = fmaxf(tm, s[r]);
    tm = fmaxf(tm, __shfl_xor(tm, 32));
    const float mn = fmaxf(m_run, tm);
    const float al = __builtin_amdgcn_exp2f((m_run - mn) * cl2e);
    m_run = mn;
    float ts = 0.f;
#pragma unroll
    for (int r = 0; r < 16; ++r) {
      const float p = __builtin_amdgcn_exp2f((s[r] - mn) * cl2e);
      s[r] = p;
      ts += p;
    }
    ts += __shfl_xor(ts, 32);
    l_run = l_run * al + ts;
    o0 *= al;
    o1 *= al;

    unsigned B0 = cvtpk(s[0], s[1]), B1 = cvtpk(s[2], s[3]);
    unsigned B2 = cvtpk(s[4], s[5]), B3 = cvtpk(s[6], s[7]);
    swap32(B0, B2);
    swap32(B1, B3);
    unsigned B4 = cvtpk(s[8], s[9]), B5 = cvtpk(s[10], s[11]);
    unsigned B6 = cvtpk(s[12], s[13]), B7 = cvtpk(s[14], s[15]);
    swap32(B4, B6);
    swap32(B5, B7);
    union U { uint4v u; short8 s8; } u0, u1;
    u0.u = (uint4v){B0, B1, B2, B3};
    u1.u = (uint4v){B4, B5, B6, B7};

    o0 = __builtin_amdgcn_mfma_f32_32x32x16_bf16(vf[0][0], u0.s8, o0, 0, 0, 0);
    o0 = __builtin_amdgcn_mfma_f32_32x32x16_bf16(vf[0][1], u1.s8, o0, 0, 0, 0);
    o1 = __builtin_amdgcn_mfma_f32_32x32x16_bf16(vf[1][0], u0.s8, o1, 0, 0, 0);
    o1 = __builtin_amdgcn_mfma_f32_32x32x16_bf16(vf[1][1], u1.s8, o1, 0, 0, 0);
  }

  const float inv = 1.0f / l_run;
  unsigned* so32 = (unsigned*)&sO[wave][0];
#pragma unroll
  for (int j2 = 0; j2 < 8; ++j2) {
    const int d0 = ((2 * j2) & 3) + 8 * (j2 >> 1) + 4 * h;  // even d of the pair
    so32[l31 * 34 + (d0 >> 1)] = cvtpk(o0[2 * j2] * inv, o0[2 * j2 + 1] * inv);
    so32[l31 * 34 + ((32 + d0) >> 1)] = cvtpk(o1[2 * j2] * inv, o1[2 * j2 + 1] * inv);
  }
#pragma unroll
  for (int p2 = 0; p2 < 4; ++p2) {
    const int rp = p2 * 8 + (lane >> 3);
    const int co = (lane & 7) * 8;
    short4v va = *(const short4v*)&sO[wave][rp * 68 + co];
    short4v vb = *(const short4v*)&sO[wave][rp * 68 + co + 4];
    unsigned short* gp = &attn[(size_t)(b * TS + qrb + rp) * TD + hh * THS + co];
    *(short4v*)gp = va;
    *(short4v*)(gp + 4) = vb;
  }
}

// ---------------- GEMM2: out = attn @ wpT^T + bias (fp32 out) ----------------
// NEW: 128M x 64N tile -> grid (16,32) = 512 blocks = 2 blocks/CU (was 256 = 1/CU, fully
// exposed barrier drains). 4 waves as 2x2, per-wave 64x32 (acc 4x2). LDS 24 KB dbuf.
// Same staging/frag/MFMA idioms as gemm_core_k1024 (proven): global_load_lds width-16,
// row-major [rows][32] tiles, identical fragment addressing.
__global__ __launch_bounds__(256) void k_gemm_proj(const unsigned short* __restrict__ A,
                                                   const unsigned short* __restrict__ BT,
                                                   const float* __restrict__ bias,
                                                   float* __restrict__ out) {
  __shared__ unsigned short sA[2 * 4096];  // 2 bufs x 128x32
  __shared__ unsigned short sB[2 * 2048];  // 2 bufs x 64x32
  const int tid = threadIdx.x;
  const int wave = tid >> 6, lane = tid & 63;
  const int wm = wave >> 1, wn = wave & 1;
  const int m0 = blockIdx.y * 128, n0 = blockIdx.x * 64;

  f32x4 acc[4][2];
#pragma unroll
  for (int mi = 0; mi < 4; ++mi)
#pragma unroll
    for (int nj = 0; nj < 2; ++nj)
      acc[mi][nj] = (f32x4){0.f, 0.f, 0.f, 0.f};

  // staging: thread t -> A chunks t (rows 0-63) and t+256 (rows 64-127), B chunk t.
  const int ar0 = tid >> 2, ak0 = (tid & 3) * 8;
  const size_t gA0 = (size_t)(m0 + ar0) * TK + ak0;
  const size_t gA1 = (size_t)(m0 + 64 + ar0) * TK + ak0;
  const size_t gB0 = (size_t)(n0 + ar0) * TK + ak0;  // ar0 < 64 for B rows

  auto stage = [&](int buf, int kt) {
    const int ko = kt * 32;
    async_copy16(A + gA0 + ko, sA + buf * 4096 + tid * 8);
    async_copy16(A + gA1 + ko, sA + buf * 4096 + 2048 + tid * 8);
    async_copy16(BT + gB0 + ko, sB + buf * 2048 + tid * 8);
  };

  stage(0, 0);
  __syncthreads();

  const int l15 = lane & 15, lk8 = (lane >> 4) * 8;
  const int aoff = (wm * 64 + l15) * 32 + lk8;
  const int boff = (wn * 32 + l15) * 32 + lk8;

  for (int kt = 0; kt < TK / 32; ++kt) {
    const int buf = kt & 1;
    if (kt + 1 < TK / 32) stage(buf ^ 1, kt + 1);
    short8 af[4], bfr[2];
#pragma unroll
    for (int i = 0; i < 4; ++i)
      af[i] = *(const short8*)&sA[buf * 4096 + aoff + i * 16 * 32];
#pragma unroll
    for (int j = 0; j < 2; ++j)
      bfr[j] = *(const short8*)&sB[buf * 2048 + boff + j * 16 * 32];
#pragma unroll
    for (int mi = 0; mi < 4; ++mi)
#pragma unroll
      for (int nj = 0; nj < 2; ++nj)
        acc[mi][nj] = __builtin_amdgcn_mfma_f32_16x16x32_bf16(af[mi], bfr[nj], acc[mi][nj], 0, 0, 0);
    __syncthreads();
  }

  const int lr4 = (lane >> 4) * 4;
#pragma unroll
  for (int mi = 0; mi < 4; ++mi) {
    const int row = m0 + wm * 64 + mi * 16 + lr4;
#pragma unroll
    for (int nj = 0; nj < 2; ++nj) {
      const int col = n0 + wn * 32 + nj * 16 + l15;
      const float bi = bias[col];
#pragma unroll
      for (int j = 0; j < 4; ++j)
        out[(size_t)(row + j) * TD + col] = acc[mi][nj][j] + bi;
    }
  }
}

extern "C" void kernel_launch(void* const* d_in, const int* in_sizes, int n_in,
                              void* d_out, int out_size, void* d_ws, size_t ws_size,
                              hipStream_t stream) {
  const float* x = (const float*)d_in[0];
  const float* c_attn_w = (const float*)d_in[1];
  const float* c_attn_b = (const float*)d_in[2];
  const float* c_proj_w = (const float*)d_in[3];
  const float* c_proj_b = (const float*)d_in[4];
  float* out = (float*)d_out;

  const size_t SZ_XB = (size_t)4096 * 1024 * 2;
  const size_t SZ_WAT = (size_t)3072 * 1024 * 2;
  const size_t SZ_WPT = (size_t)1024 * 1024 * 2;
  const size_t SZ_HEAD = (size_t)TB * TH * TS * THS * 2;
  const size_t SZ_ATT = (size_t)4096 * 1024 * 2;
  if (ws_size < SZ_XB + SZ_WAT + SZ_WPT + 3 * SZ_HEAD + SZ_ATT) return;

  char* ws = (char*)d_ws;
  unsigned short* xb = (unsigned short*)ws;   ws += SZ_XB;
  unsigned short* waT = (unsigned short*)ws;  ws += SZ_WAT;
  unsigned short* wpT = (unsigned short*)ws;  ws += SZ_WPT;
  unsigned short* Qb = (unsigned short*)ws;   ws += SZ_HEAD;
  unsigned short* Kb = (unsigned short*)ws;   ws += SZ_HEAD;
  unsigned short* VTb = (unsigned short*)ws;  ws += SZ_HEAD;
  unsigned short* attn = (unsigned short*)ws; ws += SZ_ATT;

  k_cvt_bf16x4<<<4096, 256, 0, stream>>>(x, (ushort4*)xb, 4096 * 1024 / 4);
  k_transpose_bf<<<dim3(3072 / 32, 1024 / 32), 256, 0, stream>>>(c_attn_w, waT, 1024, 3072);
  k_transpose_bf<<<dim3(1024 / 32, 1024 / 32), 256, 0, stream>>>(c_proj_w, wpT, 1024, 1024);
  k_gemm_qkv<<<dim3(3072 / 128, 4096 / 128), 256, 0, stream>>>(xb, waT, c_attn_b, Qb, Kb, VTb);
  k_attn<<<dim3(16, TH, TB), 256, 0, stream>>>(Qb, Kb, VTb, attn);
  k_gemm_proj<<<dim3(1024 / 64, 4096 / 128), 256, 0, stream>>>(attn, wpT, c_proj_b, out);
}